// Round 1
// baseline (1324.441 us; speedup 1.0000x reference)
//
#include <hip/hip_runtime.h>
#include <hip/hip_bf16.h>
#include <math.h>

// B=1024, S=512, H=512, D=2048
// risk = clip(0.25*(re/ln8) - 0.2*(1-mc) + 0.2*sigmoid(mm-2)
//             + 0.2*mean_s sigmoid(hs[b,s,:]·pw + pb)
//             + 0.15*sigmoid(1/(||rr[b]||+1e-8) - 1), 0, 1)

#define S_TOK 512
#define H_DIM 512
#define D_DIM 2048

__device__ __forceinline__ float sigmoidf_fast(float x) {
    return 1.0f / (1.0f + __expf(-x));
}

__global__ __launch_bounds__(256) void halluc_kernel(
    const float* __restrict__ routing_entropy,
    const float* __restrict__ moe_confidence,
    const float* __restrict__ memory_mismatch,
    const float* __restrict__ hidden_states,
    const float* __restrict__ routing_repr,
    const float* __restrict__ probe_w,
    const float* __restrict__ probe_b,
    float* __restrict__ out)
{
    const int b    = blockIdx.x;
    const int tid  = threadIdx.x;
    const int lane = tid & 63;
    const int wave = tid >> 6;           // 0..3

    // ---- probe weights resident in registers: 128 float4, lanes cover 2 each
    const float4* pw4 = (const float4*)probe_w;      // H_DIM/4 = 128
    const float4 w0 = pw4[lane];
    const float4 w1 = pw4[lane + 64];
    const float  pb = probe_b[0];

    // ---- semantic entropy: each wave owns tokens s = wave, wave+4, ...
    const float4* hs4 = (const float4*)(hidden_states + (size_t)b * S_TOK * H_DIM);
    float sem = 0.0f;
    #pragma unroll 2
    for (int s = wave; s < S_TOK; s += 4) {
        const float4* row = hs4 + (size_t)s * (H_DIM / 4);
        const float4 a0 = row[lane];
        const float4 a1 = row[lane + 64];
        float d = a0.x * w0.x + a0.y * w0.y + a0.z * w0.z + a0.w * w0.w
                + a1.x * w1.x + a1.y * w1.y + a1.z * w1.z + a1.w * w1.w;
        // 64-lane butterfly: every lane ends with the full dot product
        #pragma unroll
        for (int m = 32; m > 0; m >>= 1) d += __shfl_xor(d, m, 64);
        sem += sigmoidf_fast(d + pb);   // redundant across lanes; identical value
    }

    // ---- eigen score: sum of squares of routing_repr[b, 0:2048]
    const float4* rr4 = (const float4*)(routing_repr + (size_t)b * D_DIM);
    const float4 r0 = rr4[tid];          // 512 float4 total, 2 per thread
    const float4 r1 = rr4[tid + 256];
    float sq = r0.x * r0.x + r0.y * r0.y + r0.z * r0.z + r0.w * r0.w
             + r1.x * r1.x + r1.y * r1.y + r1.z * r1.z + r1.w * r1.w;
    #pragma unroll
    for (int m = 32; m > 0; m >>= 1) sq += __shfl_xor(sq, m, 64);

    __shared__ float s_sem[4];
    __shared__ float s_sq[4];
    if (lane == 0) { s_sem[wave] = sem; s_sq[wave] = sq; }
    __syncthreads();

    if (tid == 0) {
        const float sem_mean = (s_sem[0] + s_sem[1] + s_sem[2] + s_sem[3]) * (1.0f / S_TOK);
        const float sv       = sqrtf(s_sq[0] + s_sq[1] + s_sq[2] + s_sq[3]);
        const float neig     = sigmoidf_fast(1.0f / (sv + 1e-8f) - 1.0f);

        const float ne = routing_entropy[b] * 0.48089834696298783f;  // 1/ln(8)
        const float ic = 1.0f - moe_confidence[b];
        const float nm = sigmoidf_fast(memory_mismatch[b] - 2.0f);

        float risk = 0.25f * ne - 0.2f * ic + 0.2f * nm
                   + 0.2f * sem_mean + 0.15f * neig;
        risk = fminf(fmaxf(risk, 0.0f), 1.0f);
        out[b] = risk;
    }
}

extern "C" void kernel_launch(void* const* d_in, const int* in_sizes, int n_in,
                              void* d_out, int out_size, void* d_ws, size_t ws_size,
                              hipStream_t stream) {
    const float* routing_entropy = (const float*)d_in[0];
    const float* moe_confidence  = (const float*)d_in[1];
    const float* memory_mismatch = (const float*)d_in[2];
    // d_in[3] = memory_loss (unused by reference)
    const float* hidden_states   = (const float*)d_in[4];
    const float* routing_repr    = (const float*)d_in[5];
    const float* probe_w         = (const float*)d_in[6];
    const float* probe_b         = (const float*)d_in[7];
    float* out = (float*)d_out;

    const int B = in_sizes[0];  // 1024

    halluc_kernel<<<B, 256, 0, stream>>>(
        routing_entropy, moe_confidence, memory_mismatch,
        hidden_states, routing_repr, probe_w, probe_b, out);
}